// Round 3
// baseline (133.106 us; speedup 1.0000x reference)
//
#include <hip/hip_runtime.h>
#include <hip/hip_bf16.h>

// Problem constants
#define BB 16
#define SS 384
#define HH 1024
#define NH 16
#define HD 64
#define MM (BB*SS)        // 6144
#define KK HH             // 1024
#define N3 (3*HH)         // 3072

typedef float f32x4 __attribute__((ext_vector_type(4)));
typedef __bf16 bf16x8 __attribute__((ext_vector_type(8)));
typedef unsigned short us8 __attribute__((ext_vector_type(8)));
typedef unsigned short us4 __attribute__((ext_vector_type(4)));

__device__ __forceinline__ void gload_lds16(const void* g, void* l) {
    __builtin_amdgcn_global_load_lds(
        (const __attribute__((address_space(1))) void*)g,
        (__attribute__((address_space(3))) void*)l, 16, 0, 0);
}

__device__ __forceinline__ unsigned short f2b(float f) {
    __bf16 h = (__bf16)f;
    return __builtin_bit_cast(unsigned short, h);
}

// ---------------- kernel 0a: activation f32 -> bf16 ----------------
__global__ __launch_bounds__(256) void cvt_x(const float4* __restrict__ in,
                                             us4* __restrict__ out, int n4) {
    int i = blockIdx.x * 256 + threadIdx.x;
    if (i < n4) {
        float4 v = in[i];
        us4 o;
        o.x = f2b(v.x); o.y = f2b(v.y); o.z = f2b(v.z); o.w = f2b(v.w);
        out[i] = o;
    }
}

// ---------------- kernel 0b: W [K][N3] f32 -> WT [N3][K] bf16 ----------------
__global__ __launch_bounds__(256) void cvt_w(const float* __restrict__ Wf,
                                             __bf16* __restrict__ WT) {
    __shared__ float tile[32][33];
    const int n0 = blockIdx.x * 32, k0 = blockIdx.y * 32;
    const int t = threadIdx.x;
    const int tj = t & 31, ti = t >> 5;   // ti 0..7
#pragma unroll
    for (int p = 0; p < 4; ++p) {
        int i = p * 8 + ti;
        tile[i][tj] = Wf[(size_t)(k0 + i) * N3 + n0 + tj];
    }
    __syncthreads();
#pragma unroll
    for (int p = 0; p < 4; ++p) {
        int jj = p * 8 + ti;
        WT[(size_t)(n0 + jj) * KK + k0 + tj] = (__bf16)tile[tj][jj];
    }
}

// ---------------- kernel 1: QKV GEMM (m97 structure) ----------------
// C[6144][3072] = Xb[6144][1024] @ WT[3072][1024]^T + bias
// cols 0..2047 -> QKb [6144][2048]; cols 2048..3071 -> VTg [b][h][d][s]
__global__ __launch_bounds__(256) void qkv_gemm(const __bf16* __restrict__ Xb,
                                                const __bf16* __restrict__ WT,
                                                const float* __restrict__ bias,
                                                __bf16* __restrict__ QKb,
                                                __bf16* __restrict__ VTg) {
    __shared__ __bf16 As[128 * 32];
    __shared__ __bf16 Bs[128 * 32];
    const int t = threadIdx.x;
    const int w = t >> 6, lane = t & 63;
    const int wr = w >> 1, wc = w & 1;
    const int l15 = lane & 15, lg = lane >> 4;
    const int m0 = blockIdx.y * 128, n0 = blockIdx.x * 128;

    f32x4 acc[4][4] = {};

    for (int k0 = 0; k0 < KK; k0 += 32) {
        // stage A and B tiles: 8 slabs of 16 rows x 32 cols each; slab = 1KB
#pragma unroll
        for (int i = 0; i < 2; ++i) {
            int slab = w * 2 + i;
            int row = slab * 16 + (lane >> 2);
            int ck = lane & 3;
            gload_lds16(Xb + (size_t)(m0 + row) * KK + k0 + ck * 8, &As[slab * 512]);
            gload_lds16(WT + (size_t)(n0 + row) * KK + k0 + ck * 8, &Bs[slab * 512]);
        }
        __syncthreads();   // drains vmcnt -> staged data visible

        bf16x8 a[4];
#pragma unroll
        for (int i = 0; i < 4; ++i) {
            int row = wr * 64 + i * 16 + l15;
            a[i] = *(const bf16x8*)&As[row * 32 + lg * 8];
        }
#pragma unroll
        for (int j = 0; j < 4; ++j) {
            int row = wc * 64 + j * 16 + l15;
            bf16x8 bv = *(const bf16x8*)&Bs[row * 32 + lg * 8];
#pragma unroll
            for (int i = 0; i < 4; ++i)
                acc[i][j] = __builtin_amdgcn_mfma_f32_16x16x32_bf16(a[i], bv, acc[i][j], 0, 0, 0);
        }
        __syncthreads();
    }

    // epilogue: bias add, bf16 convert, scatter to QKb / VTg
#pragma unroll
    for (int j = 0; j < 4; ++j) {
        int c = n0 + wc * 64 + j * 16 + l15;
        float bv = bias[c];
#pragma unroll
        for (int i = 0; i < 4; ++i) {
#pragma unroll
            for (int r = 0; r < 4; ++r) {
                int rr = m0 + wr * 64 + i * 16 + lg * 4 + r;
                float v = acc[i][j][r] + bv;
                if (c < 2048) {
                    QKb[(size_t)rr * 2048 + c] = (__bf16)v;
                } else {
                    int d = c & 63;
                    int hh = (c - 2048) >> 6;
                    int bb = rr / SS;
                    int s = rr - bb * SS;
                    VTg[((size_t)(bb * NH + hh) * HD + d) * SS + s] = (__bf16)v;
                }
            }
        }
    }
}

// ---------------- kernel 2: fused attention per (b,h) ----------------
// LDS layout (bytes):
#define KLOFF 0                    // K   [384][64] bf16, swizzled   (49152)
#define VTOFF 49152                // V^T [64][384] bf16, swizzled   (49152)
#define PLOFF 98304                // P   [64][384] bf16, swizzled   (49152)
#define QLOFF 147456               // Q   [64][64]  bf16, swizzled   (8192)
#define MKOFF 155648               // mask[384] f32                  (1536)
#define SMEMSZ 157184

__global__ __launch_bounds__(256) void attn(const __bf16* __restrict__ QKb,
                                            const __bf16* __restrict__ VTg,
                                            const float* __restrict__ maskg,
                                            float* __restrict__ out) {
    extern __shared__ char smem[];
    const int head = blockIdx.x;
    const int b = head >> 4, h = head & 15;
    const int t = threadIdx.x;
    const int w = t >> 6, lane = t & 63;
    const int l15 = lane & 15, lg = lane >> 4;

    // ---- stage K [s][d] (rows 128B, XOR swizzle (row&7)<<4) ----
    for (int it = 0; it < 12; ++it) {
        int slot = it * 256 + t;
        int row = slot >> 3, ck = slot & 7;
        us8 v = *(const us8*)&QKb[(size_t)(b * SS + row) * 2048 + 1024 + h * 64 + ck * 8];
        int byte = (row * 128 + ck * 16) ^ ((row & 7) << 4);
        *(us8*)(smem + KLOFF + byte) = v;
    }
    // ---- stage V^T [d][s] (rows 768B, XOR swizzle (d&7)<<4) ----
    for (int it = 0; it < 12; ++it) {
        int slot = it * 256 + t;
        int d = slot / 48, ck = slot - d * 48;
        us8 v = *(const us8*)&VTg[((size_t)head * HD + d) * SS + ck * 8];
        int byte = (d * 768 + ck * 16) ^ ((d & 7) << 4);
        *(us8*)(smem + VTOFF + byte) = v;
    }
    // ---- stage mask row ----
    for (int s = t; s < SS; s += 256)
        ((float*)(smem + MKOFF))[s] = maskg[b * SS + s];
    __syncthreads();

    for (int q0 = 0; q0 < SS; q0 += 64) {
        // stage Q tile [64][64]
        for (int it = 0; it < 2; ++it) {
            int slot = it * 256 + t;
            int row = slot >> 3, ck = slot & 7;
            us8 v = *(const us8*)&QKb[(size_t)(b * SS + q0 + row) * 2048 + h * 64 + ck * 8];
            int byte = (row * 128 + ck * 16) ^ ((row & 7) << 4);
            *(us8*)(smem + QLOFF + byte) = v;
        }
        __syncthreads();

        // ---- QK^T: wave w handles q-rows [w*16, w*16+16) x all 384 k ----
        f32x4 acc[24];
#pragma unroll
        for (int f = 0; f < 24; ++f) acc[f] = f32x4{0.f, 0.f, 0.f, 0.f};
        bf16x8 aq[2];
        {
            int row = w * 16 + l15;
#pragma unroll
            for (int st = 0; st < 2; ++st)
                aq[st] = *(const bf16x8*)(smem + QLOFF +
                          ((row * 128 + st * 64 + lg * 16) ^ ((row & 7) << 4)));
        }
#pragma unroll
        for (int f = 0; f < 24; ++f) {
            int row = f * 16 + l15;
#pragma unroll
            for (int st = 0; st < 2; ++st) {
                bf16x8 kb = *(const bf16x8*)(smem + KLOFF +
                             ((row * 128 + st * 64 + lg * 16) ^ ((row & 7) << 4)));
                acc[f] = __builtin_amdgcn_mfma_f32_16x16x32_bf16(aq[st], kb, acc[f], 0, 0, 0);
            }
        }

        // ---- softmax (rows = lg*4+r, cols spread over l15 x 24 frags) ----
        const float* mrow = (const float*)(smem + MKOFF);
        float mx[4] = {-1e30f, -1e30f, -1e30f, -1e30f};
#pragma unroll
        for (int f = 0; f < 24; ++f) {
            float mk = mrow[f * 16 + l15];
#pragma unroll
            for (int r = 0; r < 4; ++r) {
                float v = acc[f][r] * 0.125f + mk;
                acc[f][r] = v;
                mx[r] = fmaxf(mx[r], v);
            }
        }
#pragma unroll
        for (int off = 8; off >= 1; off >>= 1)
#pragma unroll
            for (int r = 0; r < 4; ++r) mx[r] = fmaxf(mx[r], __shfl_xor(mx[r], off, 64));
        float sm[4] = {0.f, 0.f, 0.f, 0.f};
#pragma unroll
        for (int f = 0; f < 24; ++f)
#pragma unroll
            for (int r = 0; r < 4; ++r) {
                float p = __expf(acc[f][r] - mx[r]);
                acc[f][r] = p;
                sm[r] += p;
            }
#pragma unroll
        for (int off = 8; off >= 1; off >>= 1)
#pragma unroll
            for (int r = 0; r < 4; ++r) sm[r] += __shfl_xor(sm[r], off, 64);
        float inv[4];
#pragma unroll
        for (int r = 0; r < 4; ++r) inv[r] = 1.f / sm[r];

        // ---- write P (unnormalized) to LDS ----
#pragma unroll
        for (int f = 0; f < 24; ++f)
#pragma unroll
            for (int r = 0; r < 4; ++r) {
                int row = w * 16 + lg * 4 + r;
                int col = f * 16 + l15;
                int byte = (row * 768 + col * 2) ^ ((row & 7) << 4);
                *(__bf16*)(smem + PLOFF + byte) = (__bf16)acc[f][r];
            }
        __syncthreads();

        // ---- PV: O[16][64] per wave, K-loop over 384 in steps of 32 ----
        f32x4 o[4] = {};
#pragma unroll
        for (int st = 0; st < 12; ++st) {
            int prow = w * 16 + l15;
            bf16x8 pa = *(const bf16x8*)(smem + PLOFF +
                         ((prow * 768 + st * 64 + lg * 16) ^ ((prow & 7) << 4)));
#pragma unroll
            for (int j = 0; j < 4; ++j) {
                int d = j * 16 + l15;
                bf16x8 vb = *(const bf16x8*)(smem + VTOFF +
                             ((d * 768 + st * 64 + lg * 16) ^ ((d & 7) << 4)));
                o[j] = __builtin_amdgcn_mfma_f32_16x16x32_bf16(pa, vb, o[j], 0, 0, 0);
            }
        }

        // ---- normalize + write output (FLOAT32) [b][s][h*64+d] ----
#pragma unroll
        for (int j = 0; j < 4; ++j)
#pragma unroll
            for (int r = 0; r < 4; ++r) {
                int qrow = q0 + w * 16 + lg * 4 + r;
                out[(size_t)(b * SS + qrow) * HH + h * 64 + j * 16 + l15] =
                    o[j][r] * inv[r];
            }
    }
}

// ---------------- launch ----------------
extern "C" void kernel_launch(void* const* d_in, const int* in_sizes, int n_in,
                              void* d_out, int out_size, void* d_ws, size_t ws_size,
                              hipStream_t stream) {
    const float* act  = (const float*)d_in[0];
    const float* mask = (const float*)d_in[1];
    const float* wq   = (const float*)d_in[2];
    const float* bias = (const float*)d_in[3];

    char* ws = (char*)d_ws;
    __bf16* Xb  = (__bf16*)(ws);                       // 12,582,912 B
    __bf16* WT  = (__bf16*)(ws + 12582912);            //  6,291,456 B
    __bf16* QKb = (__bf16*)(ws + 18874368);            // 25,165,824 B
    __bf16* VTg = (__bf16*)(ws + 44040192);            // 12,582,912 B (end 56.6MB)

    cvt_x<<<(MM * KK / 4 + 255) / 256, 256, 0, stream>>>((const float4*)act, (us4*)Xb, MM * KK / 4);
    cvt_w<<<dim3(N3 / 32, KK / 32), 256, 0, stream>>>(wq, WT);
    qkv_gemm<<<dim3(N3 / 128, MM / 128), 256, 0, stream>>>(Xb, WT, bias, QKb, VTg);

    (void)hipFuncSetAttribute((const void*)attn, hipFuncAttributeMaxDynamicSharedMemorySize, SMEMSZ);
    attn<<<BB * NH, 256, SMEMSZ, stream>>>(QKb, VTg, mask, (float*)d_out);
}